// Round 6
// baseline (319.383 us; speedup 1.0000x reference)
//
#include <hip/hip_runtime.h>
#include <stdint.h>

// Problem constants: B=8, T=1024, E=1024, H=16, D=64
#define BB 8
#define TT 1024
#define EE 1024
#define HH 16
#define DD 64

// log2(e)/8: folded into Q projection so attention uses exp2 directly
#define L2E8 0.18033688011112042f

typedef __attribute__((ext_vector_type(8))) __bf16 bf16x8;
typedef __attribute__((ext_vector_type(4))) float f32x4;
typedef __attribute__((ext_vector_type(4))) unsigned short ushort4v;
typedef __attribute__((ext_vector_type(4))) unsigned int uint4v;

__device__ __forceinline__ unsigned short f2bf(float f) {
  unsigned int u = __float_as_uint(f);
  u += 0x7fffu + ((u >> 16) & 1u);   // RNE (finite data)
  return (unsigned short)(u >> 16);
}

// pack two f32 -> bf16x2 with round-half-up: 2 adds + 1 v_perm (vs ~8 ops RNE)
__device__ __forceinline__ unsigned int pk2t(float a, float b) {
  return __builtin_amdgcn_perm(__float_as_uint(b) + 0x8000u,
                               __float_as_uint(a) + 0x8000u, 0x07060302u);
}

__device__ __forceinline__ f32x4 mfma_16x16x32(bf16x8 a, bf16x8 b, f32x4 c) {
  return __builtin_amdgcn_mfma_f32_16x16x32_bf16(a, b, c, 0, 0, 0);
}

// async global->LDS, 16B per lane; LDS dest must be wave-uniform base + lane*16
__device__ __forceinline__ void async_ld16(const unsigned short* g, unsigned short* l) {
  __builtin_amdgcn_global_load_lds(
      (const __attribute__((address_space(1))) void*)g,
      (__attribute__((address_space(3))) void*)l, 16, 0, 0);
}

// -------------------- cast fp32 -> bf16 for 3 inputs + 4 weights --------------------
// 3584 blocks x 8192 elems (4 chunks/thread -> 8 outstanding loads, uint4 stores)
__global__ __launch_bounds__(256) void cast_all(
    const float* __restrict__ xq, const float* __restrict__ xk, const float* __restrict__ xv,
    const float* __restrict__ wq, const float* __restrict__ wk,
    const float* __restrict__ wv, const float* __restrict__ wo,
    unsigned short* __restrict__ ws) {
  int blk = blockIdx.x;
  const float* src; size_t dstoff; int rel;
  if (blk < 1024)       { src = xq; dstoff = 0;        rel = blk; }
  else if (blk < 2048)  { src = xk; dstoff = 8388608;  rel = blk - 1024; }
  else if (blk < 3072)  { src = xv; dstoff = 16777216; rel = blk - 2048; }
  else if (blk < 3200)  { src = wq; dstoff = 25165824; rel = blk - 3072; }
  else if (blk < 3328)  { src = wk; dstoff = 26214400; rel = blk - 3200; }
  else if (blk < 3456)  { src = wv; dstoff = 27262976; rel = blk - 3328; }
  else                  { src = wo; dstoff = 28311552; rel = blk - 3456; }
  size_t base = (size_t)rel * 8192 + (size_t)threadIdx.x * 8;
#pragma unroll
  for (int c = 0; c < 4; ++c) {
    size_t off = base + (size_t)c * 2048;
    float4 a = *(const float4*)(src + off);
    float4 b = *(const float4*)(src + off + 4);
    uint4v o;
    o.x = pk2t(a.x, a.y); o.y = pk2t(a.z, a.w);
    o.z = pk2t(b.x, b.y); o.w = pk2t(b.z, b.w);
    *(uint4v*)(ws + dstoff + off) = o;
  }
}

// -------------------- fused Q/K/V projection --------------------
// 1536 blocks. XCD swizzle: id%8 == m-tile%8, so the 8 blocks sharing one
// A-tile (n=0..7) land on the SAME XCD (id differs by multiples of 8) and are
// temporally adjacent -> A fetched from HBM once, reused from that XCD's L2.
//   [0,512):    Q = xq@Wq^T+bq, scaled by L2E8, scatter (B,H,T,D)
//   [512,1024): K = xk@Wk^T+bk, scatter (B,H,T,D)
//   [1024,1536): V^T per batch z: Wv@xv_z^T + bv[m], (B,H,D,T), pi-permuted cols
__global__ __launch_bounds__(256, 3) void fused_proj(
    const unsigned short* __restrict__ xq, const unsigned short* __restrict__ xk,
    const unsigned short* __restrict__ xv, const unsigned short* __restrict__ wq,
    const unsigned short* __restrict__ wk, const unsigned short* __restrict__ wv,
    const float* __restrict__ bq, const float* __restrict__ bk, const float* __restrict__ bv,
    unsigned short* __restrict__ Qb, unsigned short* __restrict__ Kb,
    unsigned short* __restrict__ Vtb) {
  const int id = blockIdx.x;
  const int tid = threadIdx.x;
  const int wave = tid >> 6, lane = tid & 63;
  const int quad = lane >> 4, l16 = lane & 15;
  const int wr = wave >> 1, wc = wave & 1;

  const unsigned short *A, *W;
  const float* bias;
  int mode, m0, n0;
  size_t zoff = 0;
  if (id < 512) {
    int g = id;
    mode = 0; A = xq; W = wq; bias = bq;
    m0 = ((g & 7) | ((g >> 6) << 3)) * 128; n0 = ((g >> 3) & 7) * 128;
  } else if (id < 1024) {
    int g = id - 512;
    mode = 1; A = xk; W = wk; bias = bk;
    m0 = ((g & 7) | ((g >> 6) << 3)) * 128; n0 = ((g >> 3) & 7) * 128;
  } else {
    int g = id - 1024;
    int z = g >> 6;
    mode = 2; A = wv; W = xv + (size_t)z * 1048576; bias = bv;
    m0 = (g & 7) * 128; n0 = ((g >> 3) & 7) * 128;   // wv m-tile pinned to one XCD
    zoff = (size_t)z * 1048576;
  }

  __shared__ __align__(16) unsigned short As[128 * 64];
  __shared__ __align__(16) unsigned short Bs[128 * 64];

  const unsigned short* Wb = W + (size_t)n0 * 1024;

  f32x4 acc[4][4];
#pragma unroll
  for (int i = 0; i < 4; ++i)
#pragma unroll
    for (int j = 0; j < 4; ++j) acc[i][j] = (f32x4){0.f, 0.f, 0.f, 0.f};

  const int row_s = tid >> 3, kc_s = (tid & 7) * 8;
  for (int kt = 0; kt < 16; ++kt) {
    const unsigned short* Akt = A + (size_t)m0 * 1024 + kt * 64;
    const unsigned short* Wkt = Wb + kt * 64;
#pragma unroll
    for (int i = 0; i < 4; ++i) {
      int g = i * 256 + tid;
      int row = row_s + i * 32;
      async_ld16(Akt + (size_t)row * 1024 + kc_s, As + g * 8);
      async_ld16(Wkt + (size_t)row * 1024 + kc_s, Bs + g * 8);
    }
    __syncthreads();
#pragma unroll
    for (int ks = 0; ks < 2; ++ks) {
      bf16x8 af[4], bfv[4];
      int ko = ks * 32 + quad * 8;
#pragma unroll
      for (int i = 0; i < 4; ++i)
        af[i] = *(const bf16x8*)(As + (wr * 64 + i * 16 + l16) * 64 + ko);
#pragma unroll
      for (int j = 0; j < 4; ++j)
        bfv[j] = *(const bf16x8*)(Bs + (wc * 64 + j * 16 + l16) * 64 + ko);
#pragma unroll
      for (int i = 0; i < 4; ++i)
#pragma unroll
        for (int j = 0; j < 4; ++j) acc[i][j] = mfma_16x16x32(af[i], bfv[j], acc[i][j]);
    }
    __syncthreads();
  }

  if (mode == 2) {
    size_t base = zoff;
    const int nxor = ((((l16 >> 2) + 1) & 2) ? 12 : 0);
#pragma unroll
    for (int i = 0; i < 4; ++i)
#pragma unroll
      for (int r = 0; r < 4; ++r) {
        int m = m0 + wr * 64 + i * 16 + quad * 4 + r;
        float bm = bias[m];
#pragma unroll
        for (int j = 0; j < 4; ++j) {
          int n = (n0 + wc * 64 + j * 16 + l16) ^ nxor;
          Vtb[base + (size_t)m * 1024 + n] = f2bf(acc[i][j][r] + bm);
        }
      }
  } else {
    unsigned short* Out = (mode == 0) ? Qb : Kb;
    const float scale = (mode == 0) ? L2E8 : 1.0f;
#pragma unroll
    for (int j = 0; j < 4; ++j) {
      int n = n0 + wc * 64 + j * 16 + l16;
      float bn = bias[n];
      int h = n >> 6, d = n & 63;
#pragma unroll
      for (int i = 0; i < 4; ++i)
#pragma unroll
        for (int r = 0; r < 4; ++r) {
          int m = m0 + wr * 64 + i * 16 + quad * 4 + r;
          int b = m >> 10, t = m & 1023;
          float v = (acc[i][j][r] + bn) * scale;
          Out[((size_t)((b << 4) + h) * 1024 + t) * 64 + d] = f2bf(v);
        }
    }
  }
}

// -------------------- final GEMM: out = O @ Wo^T + bo (fp32 out) --------------------
// BM=64, BN=128 -> 1024 blocks, XCD-swizzled (id%8 = m-tile%8 -> A reuse in-XCD).
// A is (B,H,T,D): m=b*1024+t, k=h*64+d
__global__ __launch_bounds__(256, 4) void gemm_out(
    const unsigned short* __restrict__ A, const unsigned short* __restrict__ Wm,
    const float* __restrict__ bias, float* __restrict__ Cout) {
  const int g = blockIdx.x;
  const int tid = threadIdx.x;
  const int wave = tid >> 6, lane = tid & 63;
  const int quad = lane >> 4, l16 = lane & 15;
  const int wr = wave >> 1, wc = wave & 1;   // wave tile: 32m x 64n
  const int n0 = ((g >> 3) & 7) * 128;
  const int m0 = ((g & 7) | ((g >> 6) << 3)) * 64;

  __shared__ __align__(16) unsigned short As[64 * 64];
  __shared__ __align__(16) unsigned short Bs[128 * 64];

  const unsigned short* Wb = Wm + (size_t)n0 * 1024;

  f32x4 acc[2][4];
#pragma unroll
  for (int i = 0; i < 2; ++i)
#pragma unroll
    for (int j = 0; j < 4; ++j) acc[i][j] = (f32x4){0.f, 0.f, 0.f, 0.f};

  const int row_s = tid >> 3, kc_s = (tid & 7) * 8;
  for (int kt = 0; kt < 16; ++kt) {
    const unsigned short* Akt =
        A + (size_t)(m0 >> 10) * 1048576 + (size_t)kt * 65536 + (size_t)(m0 & 1023) * 64;
    const unsigned short* Wkt = Wb + kt * 64;
#pragma unroll
    for (int i = 0; i < 2; ++i) {
      int row = row_s + i * 32;
      async_ld16(Akt + (size_t)row * 64 + kc_s, As + (i * 256 + tid) * 8);
    }
#pragma unroll
    for (int i = 0; i < 4; ++i) {
      int row = row_s + i * 32;
      async_ld16(Wkt + (size_t)row * 1024 + kc_s, Bs + (i * 256 + tid) * 8);
    }
    __syncthreads();
#pragma unroll
    for (int ks = 0; ks < 2; ++ks) {
      bf16x8 af[2], bfv[4];
      int ko = ks * 32 + quad * 8;
#pragma unroll
      for (int i = 0; i < 2; ++i)
        af[i] = *(const bf16x8*)(As + (wr * 32 + i * 16 + l16) * 64 + ko);
#pragma unroll
      for (int j = 0; j < 4; ++j)
        bfv[j] = *(const bf16x8*)(Bs + (wc * 64 + j * 16 + l16) * 64 + ko);
#pragma unroll
      for (int i = 0; i < 2; ++i)
#pragma unroll
        for (int j = 0; j < 4; ++j) acc[i][j] = mfma_16x16x32(af[i], bfv[j], acc[i][j]);
    }
    __syncthreads();
  }

#pragma unroll
  for (int j = 0; j < 4; ++j) {
    int n = n0 + wc * 64 + j * 16 + l16;
    float bn = bias[n];
#pragma unroll
    for (int i = 0; i < 2; ++i)
#pragma unroll
      for (int r = 0; r < 4; ++r) {
        int m = m0 + wr * 32 + i * 16 + quad * 4 + r;
        Cout[(size_t)m * 1024 + n] = acc[i][j][r] + bn;
      }
  }
}

// -------------------- attention: S^T form + double-buffered K/V LDS tiles --------------------
// grid (128, 16); 4 waves x 16 q-rows; kv chunk 64/iter.
// Double buffer: stage(it+1) issued BEFORE compute(it) -> staging overlaps compute;
// the single barrier's vmcnt(0) drain completes exactly when tile it+1 is needed.
// S^T = K·Q^T; exp2 (log2e folded into Q); denominator via all-ones-B MFMA;
// PV A-frag built from exp'd S^T frags via shfl_xor(32) with kv-permutation pi;
// Vt columns pre-permuted by pi so V B-frags are contiguous 16B LDS loads.
__global__ __launch_bounds__(256) void attn(
    const unsigned short* __restrict__ Q,   // (B,H,T,D), pre-scaled by log2e/8
    const unsigned short* __restrict__ K,   // (B,H,T,D)
    const unsigned short* __restrict__ Vt,  // (B,H,D,T), T pi-permuted per 32-block
    unsigned short* __restrict__ O) {       // (B,H,T,D)
  const int bh = blockIdx.x;
  const int tid = threadIdx.x;
  const int wave = tid >> 6, lane = tid & 63;
  const int quad = lane >> 4, l16 = lane & 15;
  const int q0 = blockIdx.y * 64 + wave * 16;
  const size_t bhTD = (size_t)bh * (TT * DD);
  const unsigned short* Qb = Q + bhTD;
  const unsigned short* Kb = K + bhTD;
  const unsigned short* Vb = Vt + bhTD;

  __shared__ __align__(16) unsigned short Ks[2][64 * 64];
  __shared__ __align__(16) unsigned short Vs[2][64 * 64];

  bf16x8 q_lo = *(const bf16x8*)(Qb + (size_t)(q0 + l16) * 64 + quad * 8);
  bf16x8 q_hi = *(const bf16x8*)(Qb + (size_t)(q0 + l16) * 64 + 32 + quad * 8);

  uint4v ou; ou.x = ou.y = ou.z = ou.w = 0x3F803F80u;   // bf16 1.0 x8
  const bf16x8 ones = __builtin_bit_cast(bf16x8, ou);

  f32x4 o_acc[4];
#pragma unroll
  for (int dd = 0; dd < 4; ++dd) o_acc[dd] = (f32x4){0.f, 0.f, 0.f, 0.f};
  f32x4 acc5 = (f32x4){0.f, 0.f, 0.f, 0.f};             // per-row sum of P-hat
  const bool lo_half = (quad < 2);

  const int srow = tid >> 3;
  const int schunk = tid & 7;

#define STAGE(IT, BUF)                                                                 \
  {                                                                                    \
    const int kv0s = (IT) * 64;                                                        \
    _Pragma("unroll") for (int i = 0; i < 2; ++i) {                                    \
      int row = srow + i * 32;                                                         \
      int gc = schunk ^ (row & 7);                                                     \
      async_ld16(Kb + (size_t)(kv0s + row) * 64 + gc * 8,                              \
                 Ks[BUF] + (row * 8 + schunk) * 8);                                    \
      async_ld16(Vb + (size_t)row * 1024 + kv0s + gc * 8,                              \
                 Vs[BUF] + (row * 8 + schunk) * 8);                                    \
    }                                                                                  \
  }

  STAGE(0, 0);
  __syncthreads();

  for (int it = 0; it < 16; ++it) {
    const int buf = it & 1;
    if (it < 15) STAGE(it + 1, buf ^ 1);

    // ---- phase 1: all S-MFMAs for both 32-kv halves ----
    f32x4 f[4];
#pragma unroll
    for (int c = 0; c < 2; ++c) {
      const int r0 = c * 32 + l16;
      const int r1 = r0 + 16;
      const int sw = r0 & 7;
      bf16x8 k00 = *(const bf16x8*)(Ks[buf] + (r0 * 8 + (quad ^ sw)) * 8);
      bf16x8 k01 = *(const bf16x8*)(Ks[buf] + (r0 * 8 + ((quad + 4) ^ sw)) * 8);
      bf16x8 k10 = *(const bf16x8*)(Ks[buf] + (r1 * 8 + (quad ^ sw)) * 8);
      bf16x8 k11 = *(const bf16x8*)(Ks[buf] + (r1 * 8 + ((quad + 4) ^ sw)) * 8);
      f32x4 a = (f32x4){0.f, 0.f, 0.f, 0.f};
      f32x4 b = (f32x4){0.f, 0.f, 0.f, 0.f};
      a = mfma_16x16x32(k00, q_lo, a);
      a = mfma_16x16x32(k01, q_hi, a);
      b = mfma_16x16x32(k10, q_lo, b);
      b = mfma_16x16x32(k11, q_hi, b);
      f[2 * c] = a; f[2 * c + 1] = b;
    }

    // ---- phase 2: exp2, pack, A-frag build, denominator + PV MFMAs ----
#pragma unroll
    for (int c = 0; c < 2; ++c) {
      f32x4 f0 = f[2 * c], f1 = f[2 * c + 1];
      float p0 = __builtin_amdgcn_exp2f(f0[0]), p1 = __builtin_amdgcn_exp2f(f0[1]);
      float p2 = __builtin_amdgcn_exp2f(f0[2]), p3 = __builtin_amdgcn_exp2f(f0[3]);
      float p4 = __builtin_amdgcn_exp2f(f1[0]), p5 = __builtin_amdgcn_exp2f(f1[1]);
      float p6 = __builtin_amdgcn_exp2f(f1[2]), p7 = __builtin_amdgcn_exp2f(f1[3]);
      unsigned int u01 = pk2t(p0, p1), u23 = pk2t(p2, p3);
      unsigned int u45 = pk2t(p4, p5), u67 = pk2t(p6, p7);
      unsigned int pu01 = __shfl_xor(u01, 32), pu23 = __shfl_xor(u23, 32);
      unsigned int pu45 = __shfl_xor(u45, 32), pu67 = __shfl_xor(u67, 32);
      uint4v av;
      av.x = lo_half ? u01 : pu45;
      av.y = lo_half ? u23 : pu67;
      av.z = lo_half ? pu01 : u45;
      av.w = lo_half ? pu23 : u67;
      bf16x8 ap = __builtin_bit_cast(bf16x8, av);
      acc5 = mfma_16x16x32(ap, ones, acc5);
#pragma unroll
      for (int dd = 0; dd < 4; ++dd) {
        int vr = dd * 16 + l16;
        bf16x8 bv = *(const bf16x8*)(Vs[buf] + (vr * 8 + ((c * 4 + quad) ^ (vr & 7))) * 8);
        o_acc[dd] = mfma_16x16x32(ap, bv, o_acc[dd]);
      }
    }
    __syncthreads();
  }
#undef STAGE

#pragma unroll
  for (int r = 0; r < 4; ++r) {
    float invr = 1.f / acc5[r];    // acc5[r] = sum_k P[q=quad*4+r][k], same at every lane
    int trow = q0 + quad * 4 + r;
#pragma unroll
    for (int dd = 0; dd < 4; ++dd)
      O[bhTD + (size_t)trow * 64 + dd * 16 + l16] = f2bf(o_acc[dd][r] * invr);
  }
}

// -------------------- launch --------------------
extern "C" void kernel_launch(void* const* d_in, const int* in_sizes, int n_in,
                              void* d_out, int out_size, void* d_ws, size_t ws_size,
                              hipStream_t stream) {
  const float* xq = (const float*)d_in[0];
  const float* xk = (const float*)d_in[1];
  const float* xv = (const float*)d_in[2];
  const float* Wq = (const float*)d_in[3];
  const float* bq = (const float*)d_in[4];
  const float* Wk = (const float*)d_in[5];
  const float* bk = (const float*)d_in[6];
  const float* Wv = (const float*)d_in[7];
  const float* bv = (const float*)d_in[8];
  const float* Wo = (const float*)d_in[9];
  const float* bo = (const float*)d_in[10];

  unsigned short* ws = (unsigned short*)d_ws;
  unsigned short* xq_b = ws;                 // 8388608
  unsigned short* xk_b = ws + 8388608;
  unsigned short* xv_b = ws + 16777216;
  unsigned short* wq_b = ws + 25165824;      // 1048576 each
  unsigned short* wk_b = ws + 26214400;
  unsigned short* wv_b = ws + 27262976;
  unsigned short* wo_b = ws + 28311552;
  unsigned short* Qbuf = ws + 29360128;      // (B,H,T,D)
  unsigned short* Kbuf = ws + 37748736;      // (B,H,T,D)
  unsigned short* Vtb  = ws + 46137344;      // (B,H,D,T) pi-permuted
  unsigned short* Obuf = ws + 54525952;      // (B,H,T,D)

  cast_all<<<3584, 256, 0, stream>>>(xq, xk, xv, Wq, Wk, Wv, Wo, ws);

  fused_proj<<<1536, 256, 0, stream>>>(xq_b, xk_b, xv_b, wq_b, wk_b, wv_b,
                                       bq, bk, bv, Qbuf, Kbuf, Vtb);
  attn<<<dim3(128, 16), 256, 0, stream>>>(Qbuf, Kbuf, Vtb, Obuf);
  gemm_out<<<1024, 256, 0, stream>>>(Obuf, wo_b, bo, (float*)d_out);
}